// Round 2
// baseline (3749.804 us; speedup 1.0000x reference)
//
#include <hip/hip_runtime.h>
#include <hip/hip_bf16.h>

// Shapes (fixed by the reference): B=32, T=2048, D=512, H=128.
#define Bx 32
#define Tt 2048
#define Dd 512
#define Hh 128

// ---------------------------------------------------------------------------
// Phase 1: G[b,t,g,j] = sum_d x[b,t,d] * W_g[d,j]
// GEMM: M = B*T = 65536, K = D = 512, N = 4*H = 512.
// ---------------------------------------------------------------------------
__global__ __launch_bounds__(256) void gemm_xw(
    const float* __restrict__ X,
    const float* __restrict__ W0, const float* __restrict__ W1,
    const float* __restrict__ W2, const float* __restrict__ W3,
    float* __restrict__ G)
{
    __shared__ __align__(16) float As[16][68];
    __shared__ __align__(16) float Bs[16][64];

    const int tid = threadIdx.x;
    const int n0 = blockIdx.x * 64;
    const int m0 = blockIdx.y * 64;

    const int gate = n0 >> 7;
    const int jj0  = n0 & 127;
    const float* __restrict__ W = (gate == 0) ? W0 : (gate == 1) ? W1 : (gate == 2) ? W2 : W3;

    const int ac = tid & 15, ar = tid >> 4;
    const int bn = tid & 63, bk = tid >> 6;
    const int tx = tid & 15, ty = tid >> 4;

    float acc[4][4] = {};

    for (int k0 = 0; k0 < Dd; k0 += 16) {
        #pragma unroll
        for (int rr = 0; rr < 4; ++rr)
            As[ac][ar + rr * 16] = X[(size_t)(m0 + ar + rr * 16) * Dd + k0 + ac];
        #pragma unroll
        for (int kk = 0; kk < 4; ++kk)
            Bs[bk + kk * 4][bn] = W[(k0 + bk + kk * 4) * Hh + jj0 + bn];
        __syncthreads();

        #pragma unroll
        for (int k = 0; k < 16; ++k) {
            float4 a4 = *(const float4*)&As[k][ty * 4];
            float4 b4 = *(const float4*)&Bs[k][tx * 4];
            float a[4] = {a4.x, a4.y, a4.z, a4.w};
            float b[4] = {b4.x, b4.y, b4.z, b4.w};
            #pragma unroll
            for (int i = 0; i < 4; ++i)
                #pragma unroll
                for (int q = 0; q < 4; ++q)
                    acc[i][q] += a[i] * b[q];
        }
        __syncthreads();
    }

    #pragma unroll
    for (int i = 0; i < 4; ++i) {
        float4 r = make_float4(acc[i][0], acc[i][1], acc[i][2], acc[i][3]);
        *(float4*)&G[(size_t)(m0 + ty * 4 + i) * 512 + n0 + tx * 4] = r;
    }
}

// ---------------------------------------------------------------------------
// Phase 2: sequential scan. One block per batch element, 512 threads:
// thread (g = tid>>7, j = tid&127) owns gate g, column j.
// U_g[:,j] resident in 128 VGPRs (launch_bounds(512,2) -> 256-VGPR budget).
// ---------------------------------------------------------------------------
__global__ __launch_bounds__(512, 2) void lstm_scan(
    const float* __restrict__ G,
    const float* __restrict__ Uf, const float* __restrict__ Ui,
    const float* __restrict__ Uo, const float* __restrict__ Uc,
    const float* __restrict__ bf_, const float* __restrict__ bi_,
    const float* __restrict__ bo_, const float* __restrict__ bc_,
    const float* __restrict__ lnfg, const float* __restrict__ lnfb,
    const float* __restrict__ lnig, const float* __restrict__ lnib,
    const float* __restrict__ lnog, const float* __restrict__ lnob,
    const float* __restrict__ lncg, const float* __restrict__ lncb,
    const float* __restrict__ h0, const float* __restrict__ c0,
    const int* __restrict__ zmask,
    float* __restrict__ out, float* __restrict__ hT)
{
    const int b   = blockIdx.x;
    const int tid = threadIdx.x;
    const int g   = tid >> 7;
    const int j   = tid & 127;
    const int wave = tid >> 6;   // 0..7; gate g owns waves 2g, 2g+1

    const float* __restrict__ U  = (g == 0) ? Uf : (g == 1) ? Ui : (g == 2) ? Uo : Uc;
    const float* __restrict__ bg = (g == 0) ? bf_ : (g == 1) ? bi_ : (g == 2) ? bo_ : bc_;
    const float* __restrict__ lg = (g == 0) ? lnfg : (g == 1) ? lnig : (g == 2) ? lnog : lncg;
    const float* __restrict__ lb = (g == 0) ? lnfb : (g == 1) ? lnib : (g == 2) ? lnob : lncb;

    float u[Hh];
    #pragma unroll
    for (int k = 0; k < Hh; ++k) u[k] = U[k * Hh + j];
    const float bb  = bg[j];
    const float gam = lg[j];
    const float bet = lb[j];

    __shared__ __align__(16) float h_sh[Hh];
    __shared__ float gates[512];
    __shared__ __align__(8) float2 red[8];   // [wave] = (sum, sumsq)
    __shared__ int   zm_sh[Tt];

    // stage zoneout mask into LDS (one-time)
    for (int t = tid; t < Tt; t += 512) zm_sh[t] = zmask[t];

    if (tid < Hh) h_sh[tid] = h0[b * Hh + tid];
    float c = (tid < Hh) ? c0[b * Hh + tid] : 0.f;
    __syncthreads();

    const float* __restrict__ Gb   = G   + (size_t)b * Tt * 512;
    float* __restrict__       outb = out + (size_t)b * Tt * Hh;

    float gcur = Gb[tid];                   // prefetch t=0

    for (int t = 0; t < Tt; ++t) {
        const int tn = (t + 1 < Tt) ? t + 1 : t;
        float gnext = Gb[tn * 512 + tid];   // prefetch next step (latency hidden)

        // s = xW + b + h @ U, 4 independent accumulator chains
        float a0 = 0.f, a1 = 0.f, a2 = 0.f, a3 = 0.f;
        #pragma unroll
        for (int k = 0; k < Hh; k += 16) {
            float4 h0_ = *(const float4*)&h_sh[k];
            float4 h1_ = *(const float4*)&h_sh[k + 4];
            float4 h2_ = *(const float4*)&h_sh[k + 8];
            float4 h3_ = *(const float4*)&h_sh[k + 12];
            a0 += h0_.x * u[k]      + h0_.y * u[k + 1]  + h0_.z * u[k + 2]  + h0_.w * u[k + 3];
            a1 += h1_.x * u[k + 4]  + h1_.y * u[k + 5]  + h1_.z * u[k + 6]  + h1_.w * u[k + 7];
            a2 += h2_.x * u[k + 8]  + h2_.y * u[k + 9]  + h2_.z * u[k + 10] + h2_.w * u[k + 11];
            a3 += h3_.x * u[k + 12] + h3_.y * u[k + 13] + h3_.z * u[k + 14] + h3_.w * u[k + 15];
        }
        float s = gcur + bb + ((a0 + a1) + (a2 + a3));
        gcur = gnext;

        // LayerNorm reduction over the gate's 128 threads (= 2 waves)
        float sm = s, sq = s * s;
        #pragma unroll
        for (int off = 32; off > 0; off >>= 1) {
            sm += __shfl_xor(sm, off);
            sq += __shfl_xor(sq, off);
        }
        if ((tid & 63) == 0) red[wave] = make_float2(sm, sq);
        __syncthreads();
        float2 r0 = red[g * 2];
        float2 r1 = red[g * 2 + 1];
        float tS = r0.x + r1.x;
        float tQ = r0.y + r1.y;
        float mu  = tS * (1.f / 128.f);
        float var = tQ * (1.f / 128.f) - mu * mu;
        float xn  = (s - mu) * rsqrtf(var + 1e-5f) * gam + bet;
        float v   = 1.f / (1.f + __expf(-xn));
        gates[tid] = v;
        __syncthreads();

        if (tid < Hh) {
            float f  = gates[j];
            float i  = gates[128 + j];
            float o  = gates[256 + j];
            float ch = gates[384 + j];
            int   mt = zm_sh[t];
            float hn;
            if (mt) {
                hn = h_sh[j];           // zoneout: carry h, c unchanged
            } else {
                c  = f * c + i * ch;
                hn = o * (1.f / (1.f + __expf(-c)));   // NB: sigmoid, not tanh
                h_sh[j] = hn;
            }
            outb[t * Hh + j] = hn;
        }
        __syncthreads();
    }

    if (tid < Hh) hT[b * Hh + tid] = h_sh[tid];
}

// ---------------------------------------------------------------------------
extern "C" void kernel_launch(void* const* d_in, const int* in_sizes, int n_in,
                              void* d_out, int out_size, void* d_ws, size_t ws_size,
                              hipStream_t stream)
{
    const float* x   = (const float*)d_in[0];
    const float* W_f = (const float*)d_in[1];
    const float* W_i = (const float*)d_in[2];
    const float* W_o = (const float*)d_in[3];
    const float* W_c = (const float*)d_in[4];
    const float* U_f = (const float*)d_in[5];
    const float* U_i = (const float*)d_in[6];
    const float* U_o = (const float*)d_in[7];
    const float* U_c = (const float*)d_in[8];
    const float* b_f = (const float*)d_in[9];
    const float* b_i = (const float*)d_in[10];
    const float* b_o = (const float*)d_in[11];
    const float* b_c = (const float*)d_in[12];
    const float* ln_f_g = (const float*)d_in[13];
    const float* ln_f_b = (const float*)d_in[14];
    const float* ln_i_g = (const float*)d_in[15];
    const float* ln_i_b = (const float*)d_in[16];
    const float* ln_o_g = (const float*)d_in[17];
    const float* ln_o_b = (const float*)d_in[18];
    const float* ln_c_g = (const float*)d_in[19];
    const float* ln_c_b = (const float*)d_in[20];
    const float* h0  = (const float*)d_in[21];
    const float* c0  = (const float*)d_in[22];
    const int*   zm  = (const int*)d_in[23];

    float* out = (float*)d_out;                       // [B, T, H]
    float* hT  = out + (size_t)Bx * Tt * Hh;          // [B, H]
    float* G   = (float*)d_ws;                        // [B*T, 512] = 128 MiB

    dim3 gg(512 / 64, (Bx * Tt) / 64);                // 8 x 1024
    gemm_xw<<<gg, 256, 0, stream>>>(x, W_f, W_i, W_o, W_c, G);

    lstm_scan<<<Bx, 512, 0, stream>>>(G, U_f, U_i, U_o, U_c,
                                      b_f, b_i, b_o, b_c,
                                      ln_f_g, ln_f_b, ln_i_g, ln_i_b,
                                      ln_o_g, ln_o_b, ln_c_g, ln_c_b,
                                      h0, c0, zm, out, hT);
}

// Round 3
// 2181.328 us; speedup vs baseline: 1.7190x; 1.7190x over previous
//
#include <hip/hip_runtime.h>
#include <hip/hip_bf16.h>

// Shapes (fixed by the reference): B=32, T=2048, D=512, H=128.
#define Bx 32
#define Tt 2048
#define Dd 512
#define Hh 128

typedef __attribute__((ext_vector_type(8))) short short8;   // 8 bf16 (4 VGPR)
typedef __attribute__((ext_vector_type(4))) float f32x4;    // MFMA C/D

static __device__ __forceinline__ short f2bf(float f) {
    __hip_bfloat16 h = __float2bfloat16(f);
    return *reinterpret_cast<short*>(&h);
}
static __device__ __forceinline__ float sigm(float x) {
    return 1.f / (1.f + __expf(-x));
}

// ---------------------------------------------------------------------------
// Phase 1: G[b,t,col] = x[b,t,:] @ W_gate[:,j]  (col = gate*128+j)
// GEMM: M = 65536, K = 512, N = 512. (known-good from R0, ~330us)
// ---------------------------------------------------------------------------
__global__ __launch_bounds__(256) void gemm_xw(
    const float* __restrict__ X,
    const float* __restrict__ W0, const float* __restrict__ W1,
    const float* __restrict__ W2, const float* __restrict__ W3,
    float* __restrict__ G)
{
    __shared__ __align__(16) float As[16][68];
    __shared__ __align__(16) float Bs[16][64];

    const int tid = threadIdx.x;
    const int n0 = blockIdx.x * 64;
    const int m0 = blockIdx.y * 64;

    const int gate = n0 >> 7;
    const int jj0  = n0 & 127;
    const float* __restrict__ W = (gate == 0) ? W0 : (gate == 1) ? W1 : (gate == 2) ? W2 : W3;

    const int ac = tid & 15, ar = tid >> 4;
    const int bn = tid & 63, bk = tid >> 6;
    const int tx = tid & 15, ty = tid >> 4;

    float acc[4][4] = {};

    for (int k0 = 0; k0 < Dd; k0 += 16) {
        #pragma unroll
        for (int rr = 0; rr < 4; ++rr)
            As[ac][ar + rr * 16] = X[(size_t)(m0 + ar + rr * 16) * Dd + k0 + ac];
        #pragma unroll
        for (int kk = 0; kk < 4; ++kk)
            Bs[bk + kk * 4][bn] = W[(k0 + bk + kk * 4) * Hh + jj0 + bn];
        __syncthreads();

        #pragma unroll
        for (int k = 0; k < 16; ++k) {
            float4 a4 = *(const float4*)&As[k][ty * 4];
            float4 b4 = *(const float4*)&Bs[k][tx * 4];
            float a[4] = {a4.x, a4.y, a4.z, a4.w};
            float b[4] = {b4.x, b4.y, b4.z, b4.w};
            #pragma unroll
            for (int i = 0; i < 4; ++i)
                #pragma unroll
                for (int q = 0; q < 4; ++q)
                    acc[i][q] += a[i] * b[q];
        }
        __syncthreads();
    }

    #pragma unroll
    for (int i = 0; i < 4; ++i) {
        float4 r = make_float4(acc[i][0], acc[i][1], acc[i][2], acc[i][3]);
        *(float4*)&G[(size_t)(m0 + ty * 4 + i) * 512 + n0 + tx * 4] = r;
    }
}

// ---------------------------------------------------------------------------
// Phase 2: MFMA scan. 8 blocks x 512 threads; block owns 4 batches.
// Active-step list skips zoneout steps entirely (gates multiplied by 0).
// Per active step: S[16x512] = mfma(h_bf16[16x128], U_bf16[128x512]) + G(fp32)
// -> LN (LDS bounce, shuffle stats) -> sigmoid -> c,h update in registers.
// ---------------------------------------------------------------------------
__global__ __launch_bounds__(512, 2) void lstm_scan_mfma(
    const float* __restrict__ G,
    const float* __restrict__ Uf, const float* __restrict__ Ui,
    const float* __restrict__ Uo, const float* __restrict__ Uc,
    const float* __restrict__ bf_, const float* __restrict__ bi_,
    const float* __restrict__ bo_, const float* __restrict__ bc_,
    const float* __restrict__ lnfg, const float* __restrict__ lnfb,
    const float* __restrict__ lnig, const float* __restrict__ lnib,
    const float* __restrict__ lnog, const float* __restrict__ lnob,
    const float* __restrict__ lncg, const float* __restrict__ lncb,
    const float* __restrict__ h0, const float* __restrict__ c0,
    const int* __restrict__ zmask,
    float* __restrict__ out, float* __restrict__ hT)
{
    const int tid  = threadIdx.x;
    const int lane = tid & 63;
    const int w    = tid >> 6;          // wave 0..7
    const int b0   = blockIdx.x * 4;    // 4 batches per block

    __shared__ __align__(16) short Ap[16 * 136];   // h panel bf16 [row=b][k], padded
    __shared__ __align__(16) float ST[512 * 10];   // S/gates transposed [col][b], stride 10
    __shared__ unsigned short act[Tt];
    __shared__ int nact_sh;

    // ---- B fragments: U in bf16, resident in VGPRs (64 per thread) ----
    const int gate = w >> 1;                       // wave's gate (cols w*64..w*64+63)
    const float* __restrict__ Ug = (gate == 0) ? Uf : (gate == 1) ? Ui : (gate == 2) ? Uo : Uc;
    const int n0  = w * 64;                        // global col base
    const int l15 = lane & 15;
    const int kb  = lane >> 4;                     // 0..3

    short8 bfr[4][4];                              // [n-tile][k-step]
    #pragma unroll
    for (int nt = 0; nt < 4; ++nt) {
        const int jloc = (n0 & 127) + nt * 16 + l15;   // col within gate
        #pragma unroll
        for (int ks = 0; ks < 4; ++ks) {
            short8 v;
            #pragma unroll
            for (int r = 0; r < 8; ++r) {
                const int krow = ks * 32 + kb * 8 + r;
                v[r] = f2bf(Ug[krow * Hh + jloc]);
            }
            bfr[nt][ks] = v;
        }
    }

    // ---- LN-thread constants: thread = (row = b*4+g, cl) ----
    const int rowL = tid >> 5;          // 0..15
    const int bL   = rowL >> 2;         // batch-local 0..3
    const int gL   = rowL & 3;          // gate
    const int cl   = tid & 31;
    const float* lnGp = (gL == 0) ? lnfg : (gL == 1) ? lnig : (gL == 2) ? lnog : lncg;
    const float* lnBp = (gL == 0) ? lnfb : (gL == 1) ? lnib : (gL == 2) ? lnob : lncb;
    const float* bgp  = (gL == 0) ? bf_  : (gL == 1) ? bi_  : (gL == 2) ? bo_  : bc_;
    float lgam[4], lbet[4], lbias[4];
    #pragma unroll
    for (int kk = 0; kk < 4; ++kk) {
        const int j = cl + 32 * kk;
        lgam[kk] = lnGp[j]; lbet[kk] = lnBp[j]; lbias[kk] = bgp[j];
    }

    // ---- owner state: thread = (ob = tid>>7, oj = tid&127) ----
    const int ob = tid >> 7;
    const int oj = tid & 127;
    float hval = h0[(b0 + ob) * Hh + oj];
    float cval = c0[(b0 + ob) * Hh + oj];

    // zero A panel (waste rows must be finite); stage zmask into ST
    for (int i = tid; i < 16 * 136; i += 512) Ap[i] = 0;
    int* zst = (int*)ST;
    for (int t = tid; t < Tt; t += 512) zst[t] = zmask[t];
    __syncthreads();

    Ap[ob * 136 + oj] = f2bf(hval);
    if (tid == 0) {
        int n = 0;
        for (int t = 0; t < Tt; ++t)
            if (zst[t] == 0) act[n++] = (unsigned short)t;
        nact_sh = n;
    }
    __syncthreads();
    const int nact = nact_sh;

    // out[t] = h0 for leading zoneout steps
    const int firstA = (nact > 0) ? (int)act[0] : Tt;
    for (int tt = 0; tt < firstA; ++tt)
        out[((size_t)(b0 + ob) * Tt + tt) * Hh + oj] = hval;

    // G prefetch into C-layout registers (row r -> batch b0+r; always in range)
    auto prefetchG = [&](int t, f32x4* gp) {
        #pragma unroll
        for (int nt = 0; nt < 4; ++nt)
            #pragma unroll
            for (int r = 0; r < 4; ++r)
                gp[nt][r] = G[((size_t)(b0 + r) * Tt + t) * 512 + n0 + nt * 16 + l15];
    };
    f32x4 gpre[4];
    if (nact > 0) prefetchG((int)act[0], gpre);

    for (int k = 0; k < nact; ++k) {
        const int t  = (int)act[k];
        const int t2 = (k + 1 < nact) ? (int)act[k + 1] : Tt;

        // keep U fragments pinned in VGPRs across the loop
        #pragma unroll
        for (int nt = 0; nt < 4; ++nt)
            #pragma unroll
            for (int ks = 0; ks < 4; ++ks)
                asm volatile("" : "+v"(bfr[nt][ks]));

        f32x4 C[4];
        #pragma unroll
        for (int nt = 0; nt < 4; ++nt) C[nt] = gpre[nt];

        // S = h @ U + G  (K = 128 in 4 MFMA k-steps)
        #pragma unroll
        for (int ks = 0; ks < 4; ++ks) {
            short8 a = *(const short8*)&Ap[l15 * 136 + ks * 32 + kb * 8];
            #pragma unroll
            for (int nt = 0; nt < 4; ++nt)
                C[nt] = __builtin_amdgcn_mfma_f32_16x16x32_bf16(a, bfr[nt][ks], C[nt], 0, 0, 0);
        }

        // prefetch next active step's G (latency hidden under LN phases)
        if (k + 1 < nact) prefetchG(t2, gpre);

        // write real rows 0..3 transposed: ST[col][b]
        if (lane < 16) {
            #pragma unroll
            for (int nt = 0; nt < 4; ++nt) {
                const int col = n0 + nt * 16 + l15;
                *(float2*)&ST[col * 10]     = make_float2(C[nt][0], C[nt][1]);
                *(float2*)&ST[col * 10 + 2] = make_float2(C[nt][2], C[nt][3]);
            }
        }
        __syncthreads();

        // LayerNorm + sigmoid, in place. Stats across the row's 32 lanes.
        float s[4], sm = 0.f, sq = 0.f;
        #pragma unroll
        for (int kk = 0; kk < 4; ++kk) {
            const int col = gL * 128 + cl + 32 * kk;
            s[kk] = ST[col * 10 + bL] + lbias[kk];
            sm += s[kk]; sq += s[kk] * s[kk];
        }
        #pragma unroll
        for (int off = 1; off <= 16; off <<= 1) {
            sm += __shfl_xor(sm, off);
            sq += __shfl_xor(sq, off);
        }
        const float mu   = sm * (1.f / 128.f);
        const float rstd = rsqrtf(sq * (1.f / 128.f) - mu * mu + 1e-5f);
        #pragma unroll
        for (int kk = 0; kk < 4; ++kk) {
            const int col = gL * 128 + cl + 32 * kk;
            ST[col * 10 + bL] = sigm((s[kk] - mu) * rstd * lgam[kk] + lbet[kk]);
        }
        __syncthreads();

        // owner update (this step is active by construction)
        const float gf  = ST[(0   + oj) * 10 + ob];
        const float gi  = ST[(128 + oj) * 10 + ob];
        const float go  = ST[(256 + oj) * 10 + ob];
        const float gch = ST[(384 + oj) * 10 + ob];
        cval = gf * cval + gi * gch;
        hval = go * sigm(cval);                      // NB: sigmoid, not tanh
        Ap[ob * 136 + oj] = f2bf(hval);
        for (int tt = t; tt < t2; ++tt)              // active step + trailing zoneout run
            out[((size_t)(b0 + ob) * Tt + tt) * Hh + oj] = hval;
        __syncthreads();
    }

    hT[(b0 + ob) * Hh + oj] = hval;
}

// ---------------------------------------------------------------------------
extern "C" void kernel_launch(void* const* d_in, const int* in_sizes, int n_in,
                              void* d_out, int out_size, void* d_ws, size_t ws_size,
                              hipStream_t stream)
{
    const float* x   = (const float*)d_in[0];
    const float* W_f = (const float*)d_in[1];
    const float* W_i = (const float*)d_in[2];
    const float* W_o = (const float*)d_in[3];
    const float* W_c = (const float*)d_in[4];
    const float* U_f = (const float*)d_in[5];
    const float* U_i = (const float*)d_in[6];
    const float* U_o = (const float*)d_in[7];
    const float* U_c = (const float*)d_in[8];
    const float* b_f = (const float*)d_in[9];
    const float* b_i = (const float*)d_in[10];
    const float* b_o = (const float*)d_in[11];
    const float* b_c = (const float*)d_in[12];
    const float* ln_f_g = (const float*)d_in[13];
    const float* ln_f_b = (const float*)d_in[14];
    const float* ln_i_g = (const float*)d_in[15];
    const float* ln_i_b = (const float*)d_in[16];
    const float* ln_o_g = (const float*)d_in[17];
    const float* ln_o_b = (const float*)d_in[18];
    const float* ln_c_g = (const float*)d_in[19];
    const float* ln_c_b = (const float*)d_in[20];
    const float* h0  = (const float*)d_in[21];
    const float* c0  = (const float*)d_in[22];
    const int*   zm  = (const int*)d_in[23];

    float* out = (float*)d_out;                       // [B, T, H]
    float* hT  = out + (size_t)Bx * Tt * Hh;          // [B, H]
    float* G   = (float*)d_ws;                        // [B*T, 512] = 128 MiB

    dim3 gg(512 / 64, (Bx * Tt) / 64);                // 8 x 1024
    gemm_xw<<<gg, 256, 0, stream>>>(x, W_f, W_i, W_o, W_c, G);

    lstm_scan_mfma<<<8, 512, 0, stream>>>(G, U_f, U_i, U_o, U_c,
                                          b_f, b_i, b_o, b_c,
                                          ln_f_g, ln_f_b, ln_i_g, ln_i_b,
                                          ln_o_g, ln_o_b, ln_c_g, ln_c_b,
                                          h0, c0, zm, out, hT);
}

// Round 4
// 1833.885 us; speedup vs baseline: 2.0447x; 1.1895x over previous
//
#include <hip/hip_runtime.h>
#include <hip/hip_bf16.h>

// Shapes (fixed by the reference): B=32, T=2048, D=512, H=128.
#define Bx 32
#define Tt 2048
#define Dd 512
#define Hh 128

typedef __attribute__((ext_vector_type(8))) short short8;   // 8 bf16 (4 VGPR)
typedef __attribute__((ext_vector_type(4))) float f32x4;    // MFMA C/D

static __device__ __forceinline__ short f2bf(float f) {
    __hip_bfloat16 h = __float2bfloat16(f);
    return *reinterpret_cast<short*>(&h);
}
static __device__ __forceinline__ float sigm(float x) {
    return 1.f / (1.f + __expf(-x));
}

// barrier that does NOT drain vmcnt (plain __syncthreads emits vmcnt(0) and
// would serialize the G-prefetch / out-stores onto the critical path)
#define BARRIER_LGKM() asm volatile("s_waitcnt lgkmcnt(0)\n\ts_barrier" ::: "memory")

// ---------------------------------------------------------------------------
// Phase 1: G = x @ [W_f|W_i|W_o|W_c], bf16 MFMA.
// M = 65536, N = 512, K = 512. BM=128, BN=512 (x read once), BK=32.
// 512 threads = 8 waves in 2x4 grid; per wave 64x128 = acc[4][8] 16x16 frags.
// ---------------------------------------------------------------------------
__global__ __launch_bounds__(512, 2) void gemm_xw_mfma(
    const float* __restrict__ X,
    const float* __restrict__ W0, const float* __restrict__ W1,
    const float* __restrict__ W2, const float* __restrict__ W3,
    float* __restrict__ G)
{
    __shared__ __align__(16) short As[128][40];   // [m][k] bf16, pad->80B rows (2-way banks)
    __shared__ __align__(16) short Bs[512][40];   // [n][k] bf16

    const int tid  = threadIdx.x;
    const int m0   = blockIdx.x * 128;
    const int lane = tid & 63;
    const int w    = tid >> 6;
    const int wr   = w >> 2, wc = w & 3;          // wave -> (row half, col quarter)
    const int l15  = lane & 15, kb = lane >> 4;

    // B staging: thread owns output col n = tid (col n -> gate n>>7, j = n&127)
    const int bn   = tid;
    const int gate = bn >> 7;
    const int j    = bn & 127;
    const float* __restrict__ Wg = (gate == 0) ? W0 : (gate == 1) ? W1 : (gate == 2) ? W2 : W3;

    // A staging: thread -> (row am, k-offset ak), coalesced 128B row chunks
    const int am = tid >> 2;
    const int ak = (tid & 3) * 8;

    f32x4 acc[4][8];
    #pragma unroll
    for (int mt = 0; mt < 4; ++mt)
        #pragma unroll
        for (int nt = 0; nt < 8; ++nt)
            acc[mt][nt] = (f32x4){0.f, 0.f, 0.f, 0.f};

    for (int k0 = 0; k0 < Dd; k0 += 32) {
        // stage A: 8 fp32 -> bf16
        {
            const float4* xp = (const float4*)&X[(size_t)(m0 + am) * Dd + k0 + ak];
            float4 v0 = xp[0], v1 = xp[1];
            short8 s;
            s[0] = f2bf(v0.x); s[1] = f2bf(v0.y); s[2] = f2bf(v0.z); s[3] = f2bf(v0.w);
            s[4] = f2bf(v1.x); s[5] = f2bf(v1.y); s[6] = f2bf(v1.z); s[7] = f2bf(v1.w);
            *(short8*)&As[am][ak] = s;
        }
        // stage B: gather column j of Wg over 32 k-rows (coalesced per row)
        #pragma unroll
        for (int rc = 0; rc < 4; ++rc) {
            float v[8];
            #pragma unroll
            for (int r = 0; r < 8; ++r)
                v[r] = Wg[(size_t)(k0 + rc * 8 + r) * Hh + j];
            short8 s;
            #pragma unroll
            for (int r = 0; r < 8; ++r) s[r] = f2bf(v[r]);
            *(short8*)&Bs[bn][rc * 8] = s;
        }
        __syncthreads();

        short8 a[4], b[8];
        #pragma unroll
        for (int mt = 0; mt < 4; ++mt)
            a[mt] = *(const short8*)&As[wr * 64 + mt * 16 + l15][kb * 8];
        #pragma unroll
        for (int nt = 0; nt < 8; ++nt)
            b[nt] = *(const short8*)&Bs[wc * 128 + nt * 16 + l15][kb * 8];
        #pragma unroll
        for (int mt = 0; mt < 4; ++mt)
            #pragma unroll
            for (int nt = 0; nt < 8; ++nt)
                acc[mt][nt] = __builtin_amdgcn_mfma_f32_16x16x32_bf16(a[mt], b[nt], acc[mt][nt], 0, 0, 0);
        __syncthreads();
    }

    // epilogue: C layout col=lane&15, row=(lane>>4)*4+reg (verified mapping)
    #pragma unroll
    for (int mt = 0; mt < 4; ++mt)
        #pragma unroll
        for (int nt = 0; nt < 8; ++nt)
            #pragma unroll
            for (int r = 0; r < 4; ++r)
                G[(size_t)(m0 + wr * 64 + mt * 16 + kb * 4 + r) * 512 + wc * 128 + nt * 16 + l15]
                    = acc[mt][nt][r];
}

// ---------------------------------------------------------------------------
// Phase 2: MFMA scan. 8 blocks x 512 threads; block owns 4 batches.
// Active-step list skips zoneout steps (gates multiplied by 0 there).
// In-loop barriers are lgkmcnt-only so G prefetch / out stores stay in flight.
// ---------------------------------------------------------------------------
__global__ __launch_bounds__(512, 2) void lstm_scan_mfma(
    const float* __restrict__ G,
    const float* __restrict__ Uf, const float* __restrict__ Ui,
    const float* __restrict__ Uo, const float* __restrict__ Uc,
    const float* __restrict__ bf_, const float* __restrict__ bi_,
    const float* __restrict__ bo_, const float* __restrict__ bc_,
    const float* __restrict__ lnfg, const float* __restrict__ lnfb,
    const float* __restrict__ lnig, const float* __restrict__ lnib,
    const float* __restrict__ lnog, const float* __restrict__ lnob,
    const float* __restrict__ lncg, const float* __restrict__ lncb,
    const float* __restrict__ h0, const float* __restrict__ c0,
    const int* __restrict__ zmask,
    float* __restrict__ out, float* __restrict__ hT)
{
    const int tid  = threadIdx.x;
    const int lane = tid & 63;
    const int w    = tid >> 6;          // wave 0..7
    const int b0   = blockIdx.x * 4;    // 4 batches per block

    __shared__ __align__(16) short Ap[16 * 136];   // h panel bf16 [row=b][k], padded
    __shared__ __align__(16) float ST[512 * 10];   // S/gates transposed [col][b], stride 10
    __shared__ unsigned short act[Tt];
    __shared__ int wsum[8], wpre[8];
    __shared__ int nact_sh;

    // ---- B fragments: U in bf16, resident in VGPRs/AGPRs (64 per thread) ----
    const int gate = w >> 1;                       // wave's gate (cols w*64..w*64+63)
    const float* __restrict__ Ug = (gate == 0) ? Uf : (gate == 1) ? Ui : (gate == 2) ? Uo : Uc;
    const int n0  = w * 64;                        // global col base
    const int l15 = lane & 15;
    const int kb  = lane >> 4;                     // 0..3

    short8 bfr[4][4];                              // [n-tile][k-step]
    #pragma unroll
    for (int nt = 0; nt < 4; ++nt) {
        const int jloc = (n0 & 127) + nt * 16 + l15;   // col within gate
        #pragma unroll
        for (int ks = 0; ks < 4; ++ks) {
            short8 v;
            #pragma unroll
            for (int r = 0; r < 8; ++r) {
                const int krow = ks * 32 + kb * 8 + r;
                v[r] = f2bf(Ug[krow * Hh + jloc]);
            }
            bfr[nt][ks] = v;
        }
    }

    // ---- LN-thread constants: thread = (row = b*4+g, cl) ----
    const int rowL = tid >> 5;          // 0..15
    const int bL   = rowL >> 2;         // batch-local 0..3
    const int gL   = rowL & 3;          // gate
    const int cl   = tid & 31;
    const float* lnGp = (gL == 0) ? lnfg : (gL == 1) ? lnig : (gL == 2) ? lnog : lncg;
    const float* lnBp = (gL == 0) ? lnfb : (gL == 1) ? lnib : (gL == 2) ? lnob : lncb;
    const float* bgp  = (gL == 0) ? bf_  : (gL == 1) ? bi_  : (gL == 2) ? bo_  : bc_;
    float lgam[4], lbet[4], lbias[4];
    #pragma unroll
    for (int kk = 0; kk < 4; ++kk) {
        const int j = cl + 32 * kk;
        lgam[kk] = lnGp[j]; lbet[kk] = lnBp[j]; lbias[kk] = bgp[j];
    }

    // ---- owner state: thread = (ob = tid>>7, oj = tid&127) ----
    const int ob = tid >> 7;
    const int oj = tid & 127;
    float hval = h0[(b0 + ob) * Hh + oj];
    float cval = c0[(b0 + ob) * Hh + oj];

    // zero A panel (waste rows must be finite); stage zmask
    for (int i = tid; i < 16 * 136; i += 512) Ap[i] = 0;
    int* zst = (int*)ST;
    for (int t = tid; t < Tt; t += 512) zst[t] = zmask[t];
    __syncthreads();

    Ap[ob * 136 + oj] = f2bf(hval);

    // ---- parallel active-list build (prefix scan over 512x4 flags) ----
    {
        const int base_t = tid * 4;
        const int f0 = (zst[base_t] == 0), f1 = (zst[base_t + 1] == 0);
        const int f2 = (zst[base_t + 2] == 0), f3 = (zst[base_t + 3] == 0);
        const int cnt = f0 + f1 + f2 + f3;
        int scan = cnt;                                 // inclusive wave scan
        #pragma unroll
        for (int off = 1; off <= 32; off <<= 1) {
            int v = __shfl_up(scan, off);
            if (lane >= off) scan += v;
        }
        if (lane == 63) wsum[w] = scan;
        __syncthreads();
        if (tid == 0) {
            int s = 0;
            #pragma unroll
            for (int i = 0; i < 8; ++i) { wpre[i] = s; s += wsum[i]; }
            nact_sh = s;
        }
        __syncthreads();
        int pos = wpre[w] + scan - cnt;                 // exclusive offset
        if (f0) act[pos++] = (unsigned short)(base_t);
        if (f1) act[pos++] = (unsigned short)(base_t + 1);
        if (f2) act[pos++] = (unsigned short)(base_t + 2);
        if (f3) act[pos++] = (unsigned short)(base_t + 3);
    }
    __syncthreads();
    const int nact = nact_sh;

    // out[t] = h0 for leading zoneout steps
    const int firstA = (nact > 0) ? (int)act[0] : Tt;
    for (int tt = 0; tt < firstA; ++tt)
        out[((size_t)(b0 + ob) * Tt + tt) * Hh + oj] = hval;

    // G prefetch into C-layout registers (row r -> batch b0+r)
    auto prefetchG = [&](int t, f32x4* gp) {
        #pragma unroll
        for (int nt = 0; nt < 4; ++nt)
            #pragma unroll
            for (int r = 0; r < 4; ++r)
                gp[nt][r] = G[((size_t)(b0 + r) * Tt + t) * 512 + n0 + nt * 16 + l15];
    };
    f32x4 gpre[4];
    if (nact > 0) prefetchG((int)act[0], gpre);

    for (int k = 0; k < nact; ++k) {
        const int t  = (int)act[k];
        const int t2 = (k + 1 < nact) ? (int)act[k + 1] : Tt;

        // keep U fragments pinned across the loop
        #pragma unroll
        for (int nt = 0; nt < 4; ++nt)
            #pragma unroll
            for (int ks = 0; ks < 4; ++ks)
                asm volatile("" : "+v"(bfr[nt][ks]));

        f32x4 C[4], C2[4];
        #pragma unroll
        for (int nt = 0; nt < 4; ++nt) {
            C[nt]  = gpre[nt];
            C2[nt] = (f32x4){0.f, 0.f, 0.f, 0.f};
        }

        // S = h @ U + G; two independent 2-deep MFMA chains per nt
        short8 a0 = *(const short8*)&Ap[l15 * 136 + 0 * 32 + kb * 8];
        short8 a1 = *(const short8*)&Ap[l15 * 136 + 1 * 32 + kb * 8];
        short8 a2 = *(const short8*)&Ap[l15 * 136 + 2 * 32 + kb * 8];
        short8 a3 = *(const short8*)&Ap[l15 * 136 + 3 * 32 + kb * 8];
        #pragma unroll
        for (int nt = 0; nt < 4; ++nt) {
            C[nt]  = __builtin_amdgcn_mfma_f32_16x16x32_bf16(a0, bfr[nt][0], C[nt],  0, 0, 0);
            C2[nt] = __builtin_amdgcn_mfma_f32_16x16x32_bf16(a2, bfr[nt][2], C2[nt], 0, 0, 0);
        }
        #pragma unroll
        for (int nt = 0; nt < 4; ++nt) {
            C[nt]  = __builtin_amdgcn_mfma_f32_16x16x32_bf16(a1, bfr[nt][1], C[nt],  0, 0, 0);
            C2[nt] = __builtin_amdgcn_mfma_f32_16x16x32_bf16(a3, bfr[nt][3], C2[nt], 0, 0, 0);
        }

        // prefetch next active step's G (stays in flight across lgkm-only barriers)
        if (k + 1 < nact) prefetchG(t2, gpre);

        // write real rows 0..3 transposed: ST[col][b]
        if (lane < 16) {
            #pragma unroll
            for (int nt = 0; nt < 4; ++nt) {
                const int col = n0 + nt * 16 + l15;
                *(float2*)&ST[col * 10]     = make_float2(C[nt][0] + C2[nt][0], C[nt][1] + C2[nt][1]);
                *(float2*)&ST[col * 10 + 2] = make_float2(C[nt][2] + C2[nt][2], C[nt][3] + C2[nt][3]);
            }
        }
        BARRIER_LGKM();

        // LayerNorm + sigmoid, in place. Stats across the row's 32 lanes.
        float s[4], sm = 0.f, sq = 0.f;
        #pragma unroll
        for (int kk = 0; kk < 4; ++kk) {
            const int col = gL * 128 + cl + 32 * kk;
            s[kk] = ST[col * 10 + bL] + lbias[kk];
            sm += s[kk]; sq += s[kk] * s[kk];
        }
        #pragma unroll
        for (int off = 1; off <= 16; off <<= 1) {
            sm += __shfl_xor(sm, off);
            sq += __shfl_xor(sq, off);
        }
        const float mu   = sm * (1.f / 128.f);
        const float rstd = rsqrtf(sq * (1.f / 128.f) - mu * mu + 1e-5f);
        #pragma unroll
        for (int kk = 0; kk < 4; ++kk) {
            const int col = gL * 128 + cl + 32 * kk;
            ST[col * 10 + bL] = sigm((s[kk] - mu) * rstd * lgam[kk] + lbet[kk]);
        }
        BARRIER_LGKM();

        // owner update (this step is active by construction)
        const float gf  = ST[(0   + oj) * 10 + ob];
        const float gi  = ST[(128 + oj) * 10 + ob];
        const float go  = ST[(256 + oj) * 10 + ob];
        const float gch = ST[(384 + oj) * 10 + ob];
        cval = gf * cval + gi * gch;
        hval = go * sigm(cval);                      // NB: sigmoid, not tanh
        Ap[ob * 136 + oj] = f2bf(hval);
        for (int tt = t; tt < t2; ++tt)              // active step + trailing zoneout run
            out[((size_t)(b0 + ob) * Tt + tt) * Hh + oj] = hval;
        BARRIER_LGKM();
    }

    hT[(b0 + ob) * Hh + oj] = hval;
}

// ---------------------------------------------------------------------------
extern "C" void kernel_launch(void* const* d_in, const int* in_sizes, int n_in,
                              void* d_out, int out_size, void* d_ws, size_t ws_size,
                              hipStream_t stream)
{
    const float* x   = (const float*)d_in[0];
    const float* W_f = (const float*)d_in[1];
    const float* W_i = (const float*)d_in[2];
    const float* W_o = (const float*)d_in[3];
    const float* W_c = (const float*)d_in[4];
    const float* U_f = (const float*)d_in[5];
    const float* U_i = (const float*)d_in[6];
    const float* U_o = (const float*)d_in[7];
    const float* U_c = (const float*)d_in[8];
    const float* b_f = (const float*)d_in[9];
    const float* b_i = (const float*)d_in[10];
    const float* b_o = (const float*)d_in[11];
    const float* b_c = (const float*)d_in[12];
    const float* ln_f_g = (const float*)d_in[13];
    const float* ln_f_b = (const float*)d_in[14];
    const float* ln_i_g = (const float*)d_in[15];
    const float* ln_i_b = (const float*)d_in[16];
    const float* ln_o_g = (const float*)d_in[17];
    const float* ln_o_b = (const float*)d_in[18];
    const float* ln_c_g = (const float*)d_in[19];
    const float* ln_c_b = (const float*)d_in[20];
    const float* h0  = (const float*)d_in[21];
    const float* c0  = (const float*)d_in[22];
    const int*   zm  = (const int*)d_in[23];

    float* out = (float*)d_out;                       // [B, T, H]
    float* hT  = out + (size_t)Bx * Tt * Hh;          // [B, H]
    float* G   = (float*)d_ws;                        // [B*T, 512] = 128 MiB

    gemm_xw_mfma<<<(Bx * Tt) / 128, 512, 0, stream>>>(x, W_f, W_i, W_o, W_c, G);

    lstm_scan_mfma<<<8, 512, 0, stream>>>(G, U_f, U_i, U_o, U_c,
                                          b_f, b_i, b_o, b_c,
                                          ln_f_g, ln_f_b, ln_i_g, ln_i_b,
                                          ln_o_g, ln_o_b, ln_c_g, ln_c_b,
                                          h0, c0, zm, out, hT);
}

// Round 5
// 1620.189 us; speedup vs baseline: 2.3144x; 1.1319x over previous
//
#include <hip/hip_runtime.h>
#include <hip/hip_bf16.h>

// Shapes (fixed by the reference): B=32, T=2048, D=512, H=128.
#define Bx 32
#define Tt 2048
#define Dd 512
#define Hh 128

typedef __attribute__((ext_vector_type(8))) short short8;   // 8 bf16 (4 VGPR)
typedef __attribute__((ext_vector_type(4))) float f32x4;    // MFMA C/D

static __device__ __forceinline__ short f2bf(float f) {
    __hip_bfloat16 h = __float2bfloat16(f);
    return *reinterpret_cast<short*>(&h);
}
static __device__ __forceinline__ float sigm(float x) {
    return 1.f / (1.f + __expf(-x));
}

// 16-lane-row DPP add (VALU-speed cross-lane, ~4cy vs ds_swizzle ~120cy)
template<int CTRL>
static __device__ __forceinline__ float dpp_add(float v) {
    return v + __int_as_float(__builtin_amdgcn_update_dpp(
        0, __float_as_int(v), CTRL, 0xF, 0xF, true));
}
static __device__ __forceinline__ float swz_xor16_add(float v) {
    return v + __int_as_float(__builtin_amdgcn_ds_swizzle(__float_as_int(v), 0x401F));
}

// barrier that does NOT drain vmcnt (plain __syncthreads emits vmcnt(0) and
// would serialize the G-prefetch / out-stores onto the critical path)
#define BARRIER_LGKM() asm volatile("s_waitcnt lgkmcnt(0)\n\ts_barrier" ::: "memory")

// ---------------------------------------------------------------------------
// Phase 1: G = x @ [W_f|W_i|W_o|W_c], bf16 MFMA.  (verified in R4, ~80us)
// ---------------------------------------------------------------------------
__global__ __launch_bounds__(512, 2) void gemm_xw_mfma(
    const float* __restrict__ X,
    const float* __restrict__ W0, const float* __restrict__ W1,
    const float* __restrict__ W2, const float* __restrict__ W3,
    float* __restrict__ G)
{
    __shared__ __align__(16) short As[128][40];
    __shared__ __align__(16) short Bs[512][40];

    const int tid  = threadIdx.x;
    const int m0   = blockIdx.x * 128;
    const int lane = tid & 63;
    const int w    = tid >> 6;
    const int wr   = w >> 2, wc = w & 3;
    const int l15  = lane & 15, kb = lane >> 4;

    const int bn   = tid;
    const int gate = bn >> 7;
    const int j    = bn & 127;
    const float* __restrict__ Wg = (gate == 0) ? W0 : (gate == 1) ? W1 : (gate == 2) ? W2 : W3;

    const int am = tid >> 2;
    const int ak = (tid & 3) * 8;

    f32x4 acc[4][8];
    #pragma unroll
    for (int mt = 0; mt < 4; ++mt)
        #pragma unroll
        for (int nt = 0; nt < 8; ++nt)
            acc[mt][nt] = (f32x4){0.f, 0.f, 0.f, 0.f};

    for (int k0 = 0; k0 < Dd; k0 += 32) {
        {
            const float4* xp = (const float4*)&X[(size_t)(m0 + am) * Dd + k0 + ak];
            float4 v0 = xp[0], v1 = xp[1];
            short8 s;
            s[0] = f2bf(v0.x); s[1] = f2bf(v0.y); s[2] = f2bf(v0.z); s[3] = f2bf(v0.w);
            s[4] = f2bf(v1.x); s[5] = f2bf(v1.y); s[6] = f2bf(v1.z); s[7] = f2bf(v1.w);
            *(short8*)&As[am][ak] = s;
        }
        #pragma unroll
        for (int rc = 0; rc < 4; ++rc) {
            float v[8];
            #pragma unroll
            for (int r = 0; r < 8; ++r)
                v[r] = Wg[(size_t)(k0 + rc * 8 + r) * Hh + j];
            short8 s;
            #pragma unroll
            for (int r = 0; r < 8; ++r) s[r] = f2bf(v[r]);
            *(short8*)&Bs[bn][rc * 8] = s;
        }
        __syncthreads();

        short8 a[4], b[8];
        #pragma unroll
        for (int mt = 0; mt < 4; ++mt)
            a[mt] = *(const short8*)&As[wr * 64 + mt * 16 + l15][kb * 8];
        #pragma unroll
        for (int nt = 0; nt < 8; ++nt)
            b[nt] = *(const short8*)&Bs[wc * 128 + nt * 16 + l15][kb * 8];
        #pragma unroll
        for (int mt = 0; mt < 4; ++mt)
            #pragma unroll
            for (int nt = 0; nt < 8; ++nt)
                acc[mt][nt] = __builtin_amdgcn_mfma_f32_16x16x32_bf16(a[mt], b[nt], acc[mt][nt], 0, 0, 0);
        __syncthreads();
    }

    #pragma unroll
    for (int mt = 0; mt < 4; ++mt)
        #pragma unroll
        for (int nt = 0; nt < 8; ++nt)
            #pragma unroll
            for (int r = 0; r < 4; ++r)
                G[(size_t)(m0 + wr * 64 + mt * 16 + kb * 4 + r) * 512 + wc * 128 + nt * 16 + l15]
                    = acc[mt][nt][r];
}

// ---------------------------------------------------------------------------
// Phase 2: MFMA scan. 8 blocks x 512 threads; block owns 4 batches.
// launch_bounds(512,1): grid is 8 blocks on 256 CUs -> never >1 block/CU;
// full 256-reg budget keeps U fragments + double-buffered G prefetch resident.
// ---------------------------------------------------------------------------
__global__ __launch_bounds__(512, 1) void lstm_scan_mfma(
    const float* __restrict__ G,
    const float* __restrict__ Uf, const float* __restrict__ Ui,
    const float* __restrict__ Uo, const float* __restrict__ Uc,
    const float* __restrict__ bf_, const float* __restrict__ bi_,
    const float* __restrict__ bo_, const float* __restrict__ bc_,
    const float* __restrict__ lnfg, const float* __restrict__ lnfb,
    const float* __restrict__ lnig, const float* __restrict__ lnib,
    const float* __restrict__ lnog, const float* __restrict__ lnob,
    const float* __restrict__ lncg, const float* __restrict__ lncb,
    const float* __restrict__ h0, const float* __restrict__ c0,
    const int* __restrict__ zmask,
    float* __restrict__ out, float* __restrict__ hT)
{
    const int tid  = threadIdx.x;
    const int lane = tid & 63;
    const int w    = tid >> 6;          // wave 0..7
    const int b0   = blockIdx.x * 4;    // 4 batches per block

    __shared__ __align__(16) short Ap[16 * 136];   // h panel bf16 [row=b][k], padded
    __shared__ __align__(16) float ST[512 * 10];   // S/gates transposed [col][b], stride 10
    __shared__ unsigned short act[Tt];
    __shared__ int wsum[8], wpre[8];
    __shared__ int nact_sh;

    // ---- B fragments: U in bf16, resident (64 regs per thread) ----
    const int gate = w >> 1;
    const float* __restrict__ Ug = (gate == 0) ? Uf : (gate == 1) ? Ui : (gate == 2) ? Uo : Uc;
    const int n0  = w * 64;
    const int l15 = lane & 15;
    const int kb  = lane >> 4;

    short8 bfr[4][4];
    #pragma unroll
    for (int nt = 0; nt < 4; ++nt) {
        const int jloc = (n0 & 127) + nt * 16 + l15;
        #pragma unroll
        for (int ks = 0; ks < 4; ++ks) {
            short8 v;
            #pragma unroll
            for (int r = 0; r < 8; ++r) {
                const int krow = ks * 32 + kb * 8 + r;
                v[r] = f2bf(Ug[krow * Hh + jloc]);
            }
            bfr[nt][ks] = v;
        }
    }

    // ---- LN-thread constants: thread = (rowL = bL*4+gL, cl) ----
    const int rowL = tid >> 5;
    const int bL   = rowL >> 2;
    const int gL   = rowL & 3;
    const int cl   = tid & 31;
    const float* lnGp = (gL == 0) ? lnfg : (gL == 1) ? lnig : (gL == 2) ? lnog : lncg;
    const float* lnBp = (gL == 0) ? lnfb : (gL == 1) ? lnib : (gL == 2) ? lnob : lncb;
    const float* bgp  = (gL == 0) ? bf_  : (gL == 1) ? bi_  : (gL == 2) ? bo_  : bc_;
    float lgam[4], lbet[4], lbias[4];
    #pragma unroll
    for (int kk = 0; kk < 4; ++kk) {
        const int jc = cl + 32 * kk;
        lgam[kk] = lnGp[jc]; lbet[kk] = lnBp[jc]; lbias[kk] = bgp[jc];
    }

    // ---- owner state: thread = (ob = tid>>7, oj = tid&127) ----
    const int ob = tid >> 7;
    const int oj = tid & 127;
    float hval = h0[(b0 + ob) * Hh + oj];
    float cval = c0[(b0 + ob) * Hh + oj];

    for (int i = tid; i < 16 * 136; i += 512) Ap[i] = 0;
    int* zst = (int*)ST;
    for (int t = tid; t < Tt; t += 512) zst[t] = zmask[t];
    __syncthreads();

    Ap[ob * 136 + oj] = f2bf(hval);

    // ---- parallel active-list build ----
    {
        const int base_t = tid * 4;
        const int f0 = (zst[base_t] == 0), f1 = (zst[base_t + 1] == 0);
        const int f2 = (zst[base_t + 2] == 0), f3 = (zst[base_t + 3] == 0);
        const int cnt = f0 + f1 + f2 + f3;
        int scan = cnt;
        #pragma unroll
        for (int off = 1; off <= 32; off <<= 1) {
            int v = __shfl_up(scan, off);
            if (lane >= off) scan += v;
        }
        if (lane == 63) wsum[w] = scan;
        __syncthreads();
        if (tid == 0) {
            int s = 0;
            #pragma unroll
            for (int i = 0; i < 8; ++i) { wpre[i] = s; s += wsum[i]; }
            nact_sh = s;
        }
        __syncthreads();
        int pos = wpre[w] + scan - cnt;
        if (f0) act[pos++] = (unsigned short)(base_t);
        if (f1) act[pos++] = (unsigned short)(base_t + 1);
        if (f2) act[pos++] = (unsigned short)(base_t + 2);
        if (f3) act[pos++] = (unsigned short)(base_t + 3);
    }
    __syncthreads();
    const int nact = nact_sh;

    const int firstA = (nact > 0) ? (int)act[0] : Tt;
    for (int tt = 0; tt < firstA; ++tt)
        out[((size_t)(b0 + ob) * Tt + tt) * Hh + oj] = hval;

    const float* __restrict__ Gbase = G;

// G prefetch for step t into DST[4] (C-layout: reg r = batch b0+r)
#define PREFETCH_G(tq, DST)                                                       \
    do {                                                                          \
        const int _t = (tq);                                                      \
        DST##0[0] = Gbase[((size_t)(b0 + 0) * Tt + _t) * 512 + n0 +  0 + l15];    \
        DST##0[1] = Gbase[((size_t)(b0 + 1) * Tt + _t) * 512 + n0 +  0 + l15];    \
        DST##0[2] = Gbase[((size_t)(b0 + 2) * Tt + _t) * 512 + n0 +  0 + l15];    \
        DST##0[3] = Gbase[((size_t)(b0 + 3) * Tt + _t) * 512 + n0 +  0 + l15];    \
        DST##1[0] = Gbase[((size_t)(b0 + 0) * Tt + _t) * 512 + n0 + 16 + l15];    \
        DST##1[1] = Gbase[((size_t)(b0 + 1) * Tt + _t) * 512 + n0 + 16 + l15];    \
        DST##1[2] = Gbase[((size_t)(b0 + 2) * Tt + _t) * 512 + n0 + 16 + l15];    \
        DST##1[3] = Gbase[((size_t)(b0 + 3) * Tt + _t) * 512 + n0 + 16 + l15];    \
        DST##2[0] = Gbase[((size_t)(b0 + 0) * Tt + _t) * 512 + n0 + 32 + l15];    \
        DST##2[1] = Gbase[((size_t)(b0 + 1) * Tt + _t) * 512 + n0 + 32 + l15];    \
        DST##2[2] = Gbase[((size_t)(b0 + 2) * Tt + _t) * 512 + n0 + 32 + l15];    \
        DST##2[3] = Gbase[((size_t)(b0 + 3) * Tt + _t) * 512 + n0 + 32 + l15];    \
        DST##3[0] = Gbase[((size_t)(b0 + 0) * Tt + _t) * 512 + n0 + 48 + l15];    \
        DST##3[1] = Gbase[((size_t)(b0 + 1) * Tt + _t) * 512 + n0 + 48 + l15];    \
        DST##3[2] = Gbase[((size_t)(b0 + 2) * Tt + _t) * 512 + n0 + 48 + l15];    \
        DST##3[3] = Gbase[((size_t)(b0 + 3) * Tt + _t) * 512 + n0 + 48 + l15];    \
    } while (0)

    f32x4 gA0, gA1, gA2, gA3, gB0, gB1, gB2, gB3;
    if (nact > 0) PREFETCH_G((int)act[0], gA);
    if (nact > 1) PREFETCH_G((int)act[1], gB);

#define LSTM_STEP(KK, CUR)                                                        \
    do {                                                                          \
        const int _k  = (KK);                                                     \
        const int t   = (int)act[_k];                                             \
        const int t2  = (_k + 1 < nact) ? (int)act[_k + 1] : Tt;                  \
        short8 a0 = *(const short8*)&Ap[l15 * 136 +  0 + kb * 8];                 \
        short8 a1 = *(const short8*)&Ap[l15 * 136 + 32 + kb * 8];                 \
        short8 a2 = *(const short8*)&Ap[l15 * 136 + 64 + kb * 8];                 \
        short8 a3 = *(const short8*)&Ap[l15 * 136 + 96 + kb * 8];                 \
        f32x4 C0 = CUR##0, C1 = CUR##1, C2_ = CUR##2, C3 = CUR##3;                \
        f32x4 D0 = {0,0,0,0}, D1 = {0,0,0,0}, D2 = {0,0,0,0}, D3 = {0,0,0,0};     \
        C0  = __builtin_amdgcn_mfma_f32_16x16x32_bf16(a0, bfr[0][0], C0,  0,0,0); \
        C1  = __builtin_amdgcn_mfma_f32_16x16x32_bf16(a0, bfr[1][0], C1,  0,0,0); \
        C2_ = __builtin_amdgcn_mfma_f32_16x16x32_bf16(a0, bfr[2][0], C2_, 0,0,0); \
        C3  = __builtin_amdgcn_mfma_f32_16x16x32_bf16(a0, bfr[3][0], C3,  0,0,0); \
        D0  = __builtin_amdgcn_mfma_f32_16x16x32_bf16(a2, bfr[0][2], D0,  0,0,0); \
        D1  = __builtin_amdgcn_mfma_f32_16x16x32_bf16(a2, bfr[1][2], D1,  0,0,0); \
        D2  = __builtin_amdgcn_mfma_f32_16x16x32_bf16(a2, bfr[2][2], D2,  0,0,0); \
        D3  = __builtin_amdgcn_mfma_f32_16x16x32_bf16(a2, bfr[3][2], D3,  0,0,0); \
        C0  = __builtin_amdgcn_mfma_f32_16x16x32_bf16(a1, bfr[0][1], C0,  0,0,0); \
        C1  = __builtin_amdgcn_mfma_f32_16x16x32_bf16(a1, bfr[1][1], C1,  0,0,0); \
        C2_ = __builtin_amdgcn_mfma_f32_16x16x32_bf16(a1, bfr[2][1], C2_, 0,0,0); \
        C3  = __builtin_amdgcn_mfma_f32_16x16x32_bf16(a1, bfr[3][1], C3,  0,0,0); \
        D0  = __builtin_amdgcn_mfma_f32_16x16x32_bf16(a3, bfr[0][3], D0,  0,0,0); \
        D1  = __builtin_amdgcn_mfma_f32_16x16x32_bf16(a3, bfr[1][3], D1,  0,0,0); \
        D2  = __builtin_amdgcn_mfma_f32_16x16x32_bf16(a3, bfr[2][3], D2,  0,0,0); \
        D3  = __builtin_amdgcn_mfma_f32_16x16x32_bf16(a3, bfr[3][3], D3,  0,0,0); \
        if (_k + 2 < nact) PREFETCH_G((int)act[_k + 2], CUR);                     \
        if (lane < 16) {                                                          \
            *(float2*)&ST[(n0 +  0 + l15) * 10]     = make_float2(C0[0]+D0[0], C0[1]+D0[1]); \
            *(float2*)&ST[(n0 +  0 + l15) * 10 + 2] = make_float2(C0[2]+D0[2], C0[3]+D0[3]); \
            *(float2*)&ST[(n0 + 16 + l15) * 10]     = make_float2(C1[0]+D1[0], C1[1]+D1[1]); \
            *(float2*)&ST[(n0 + 16 + l15) * 10 + 2] = make_float2(C1[2]+D1[2], C1[3]+D1[3]); \
            *(float2*)&ST[(n0 + 32 + l15) * 10]     = make_float2(C2_[0]+D2[0], C2_[1]+D2[1]); \
            *(float2*)&ST[(n0 + 32 + l15) * 10 + 2] = make_float2(C2_[2]+D2[2], C2_[3]+D2[3]); \
            *(float2*)&ST[(n0 + 48 + l15) * 10]     = make_float2(C3[0]+D3[0], C3[1]+D3[1]); \
            *(float2*)&ST[(n0 + 48 + l15) * 10 + 2] = make_float2(C3[2]+D3[2], C3[3]+D3[3]); \
        }                                                                         \
        BARRIER_LGKM();                                                           \
        float s0_ = ST[(gL * 128 + cl +  0) * 10 + bL] + lbias[0];                \
        float s1_ = ST[(gL * 128 + cl + 32) * 10 + bL] + lbias[1];                \
        float s2_ = ST[(gL * 128 + cl + 64) * 10 + bL] + lbias[2];                \
        float s3_ = ST[(gL * 128 + cl + 96) * 10 + bL] + lbias[3];                \
        float sm = (s0_ + s1_) + (s2_ + s3_);                                     \
        float sq = s0_*s0_ + s1_*s1_ + s2_*s2_ + s3_*s3_;                         \
        sm = dpp_add<0xB1>(sm);  sq = dpp_add<0xB1>(sq);                          \
        sm = dpp_add<0x4E>(sm);  sq = dpp_add<0x4E>(sq);                          \
        sm = dpp_add<0x124>(sm); sq = dpp_add<0x124>(sq);                         \
        sm = dpp_add<0x128>(sm); sq = dpp_add<0x128>(sq);                         \
        sm = swz_xor16_add(sm);  sq = swz_xor16_add(sq);                          \
        const float mu   = sm * (1.f / 128.f);                                    \
        const float rstd = rsqrtf(sq * (1.f / 128.f) - mu * mu + 1e-5f);          \
        ST[(gL * 128 + cl +  0) * 10 + bL] = sigm((s0_ - mu) * rstd * lgam[0] + lbet[0]); \
        ST[(gL * 128 + cl + 32) * 10 + bL] = sigm((s1_ - mu) * rstd * lgam[1] + lbet[1]); \
        ST[(gL * 128 + cl + 64) * 10 + bL] = sigm((s2_ - mu) * rstd * lgam[2] + lbet[2]); \
        ST[(gL * 128 + cl + 96) * 10 + bL] = sigm((s3_ - mu) * rstd * lgam[3] + lbet[3]); \
        BARRIER_LGKM();                                                           \
        const float gf  = ST[(0   + oj) * 10 + ob];                               \
        const float gi  = ST[(128 + oj) * 10 + ob];                               \
        const float go  = ST[(256 + oj) * 10 + ob];                               \
        const float gch = ST[(384 + oj) * 10 + ob];                               \
        cval = gf * cval + gi * gch;                                              \
        hval = go * sigm(cval);                                                   \
        Ap[ob * 136 + oj] = f2bf(hval);                                           \
        for (int tt = t; tt < t2; ++tt)                                           \
            out[((size_t)(b0 + ob) * Tt + tt) * Hh + oj] = hval;                  \
        BARRIER_LGKM();                                                           \
    } while (0)

    for (int k = 0; k < nact; k += 2) {
        LSTM_STEP(k, gA);
        if (k + 1 < nact) LSTM_STEP(k + 1, gB);
    }

    hT[(b0 + ob) * Hh + oj] = hval;
#undef LSTM_STEP
#undef PREFETCH_G
}

// ---------------------------------------------------------------------------
extern "C" void kernel_launch(void* const* d_in, const int* in_sizes, int n_in,
                              void* d_out, int out_size, void* d_ws, size_t ws_size,
                              hipStream_t stream)
{
    const float* x   = (const float*)d_in[0];
    const float* W_f = (const float*)d_in[1];
    const float* W_i = (const float*)d_in[2];
    const float* W_o = (const float*)d_in[3];
    const float* W_c = (const float*)d_in[4];
    const float* U_f = (const float*)d_in[5];
    const float* U_i = (const float*)d_in[6];
    const float* U_o = (const float*)d_in[7];
    const float* U_c = (const float*)d_in[8];
    const float* b_f = (const float*)d_in[9];
    const float* b_i = (const float*)d_in[10];
    const float* b_o = (const float*)d_in[11];
    const float* b_c = (const float*)d_in[12];
    const float* ln_f_g = (const float*)d_in[13];
    const float* ln_f_b = (const float*)d_in[14];
    const float* ln_i_g = (const float*)d_in[15];
    const float* ln_i_b = (const float*)d_in[16];
    const float* ln_o_g = (const float*)d_in[17];
    const float* ln_o_b = (const float*)d_in[18];
    const float* ln_c_g = (const float*)d_in[19];
    const float* ln_c_b = (const float*)d_in[20];
    const float* h0  = (const float*)d_in[21];
    const float* c0  = (const float*)d_in[22];
    const int*   zm  = (const int*)d_in[23];

    float* out = (float*)d_out;                       // [B, T, H]
    float* hT  = out + (size_t)Bx * Tt * Hh;          // [B, H]
    float* G   = (float*)d_ws;                        // [B*T, 512] = 128 MiB

    gemm_xw_mfma<<<(Bx * Tt) / 128, 512, 0, stream>>>(x, W_f, W_i, W_o, W_c, G);

    lstm_scan_mfma<<<8, 512, 0, stream>>>(G, U_f, U_i, U_o, U_c,
                                          b_f, b_i, b_o, b_c,
                                          ln_f_g, ln_f_b, ln_i_g, ln_i_b,
                                          ln_o_g, ln_o_b, ln_c_g, ln_c_b,
                                          h0, c0, zm, out, hT);
}